// Round 9
// baseline (253.748 us; speedup 1.0000x reference)
//
#include <hip/hip_runtime.h>
#include <math.h>

// B=4, S=1024, D=768, H=12, E=64, 3D=2304
// Workspace layout (bytes), total ~137 MB:
//   scbuf fp16 scores -> fp16 probs in place : 100,663,296 @ 0
//     layout [b][q][h][k] head-minor (head stride 1024 u16, q stride 12*1024)
//   qkf  fp16 [4096][1536] (Q,K)  : 12,582,912 @ 100,663,296
//   vbuf fp16 [4096][768]  (V)    :  6,291,456 @ 113,246,208
//   ctx  fp16 [4096][768]         :  6,291,456 @ 119,537,664
//   x_h  fp16 :  6,291,456 @ 125,829,120
//   wq_h fp16 :  3,538,944 @ 132,120,576
//   wp_h fp16 :  1,179,648 @ 135,659,520
//
// R9 (k_mix only vs R8): exp2f (precise OCML, +13us regression in R8) replaced
// by inline-asm v_exp_f32 (native 2^x, single trans op). L2E stays folded into
// Awl/blv. Flipped mix2 (ushort4 stores) kept — proven correct, fewer stores.

typedef _Float16 f16;
typedef __attribute__((ext_vector_type(8))) _Float16 f16x8;
typedef __attribute__((ext_vector_type(4))) _Float16 f16x4;
typedef __attribute__((ext_vector_type(2))) _Float16 f16x2;
typedef __attribute__((ext_vector_type(4))) float f32x4;
typedef __attribute__((ext_vector_type(2))) float f32x2;
typedef __attribute__((ext_vector_type(2))) unsigned u32x2;
typedef unsigned short u16;

__device__ __forceinline__ u16 f2h(float f) {      // RTN convert
  f16 h = (f16)f;
  return __builtin_bit_cast(u16, h);
}
__device__ __forceinline__ unsigned pk2h(float a, float b) {
  return __builtin_bit_cast(unsigned, __builtin_amdgcn_cvt_pkrtz(a, b));
}
__device__ __forceinline__ float exp2_native(float x) {   // D = 2^S0
  float r;
  asm("v_exp_f32 %0, %1" : "=v"(r) : "v"(x));
  return r;
}

__device__ __forceinline__ void async16(const void* g, void* l) {
  __builtin_amdgcn_global_load_lds(
      (const __attribute__((address_space(1))) unsigned int*)g,
      (__attribute__((address_space(3))) unsigned int*)l, 16, 0, 0);
}

#define MFMA_F16(a, b, c) __builtin_amdgcn_mfma_f32_16x16x32_f16((a), (b), (c), 0, 0, 0)
#define MFMA16(a, b, c) __builtin_amdgcn_mfma_f32_16x16x16f16((a), (b), (c), 0, 0, 0)

// ---------------- prep: cast x, Wqkv, Wp to fp16 ----------------
__global__ __launch_bounds__(256) void k_prep(const float* __restrict__ x,
                                              const float* __restrict__ Wqkv,
                                              const float* __restrict__ Wp,
                                              u16* __restrict__ xh,
                                              u16* __restrict__ wh,
                                              u16* __restrict__ wph) {
  const int blk = blockIdx.x, t = threadIdx.x;
  if (blk < 3072) {
    int i = blk * 256 + t;
    float4 v = ((const float4*)x)[i];
    ((ushort4*)xh)[i] = make_ushort4(f2h(v.x), f2h(v.y), f2h(v.z), f2h(v.w));
  } else if (blk < 4800) {
    int i = (blk - 3072) * 256 + t;
    float4 v = ((const float4*)Wqkv)[i];
    ((ushort4*)wh)[i] = make_ushort4(f2h(v.x), f2h(v.y), f2h(v.z), f2h(v.w));
  } else {
    int i = (blk - 4800) * 256 + t;
    float4 v = ((const float4*)Wp)[i];
    ((ushort4*)wph)[i] = make_ushort4(f2h(v.x), f2h(v.y), f2h(v.z), f2h(v.w));
  }
}

// ---------------- K1: qkv = x @ Wqkv^T, fp16 single-MFMA ----------------
__global__ __launch_bounds__(256) void k_qkv(const u16* __restrict__ Axh,
                                             const u16* __restrict__ Bwh,
                                             u16* __restrict__ qkf,
                                             u16* __restrict__ vbuf) {
  __shared__ u16 smem[16384];
  u16* As = smem;
  u16* Bs = smem + 4096;
  const int t = threadIdx.x, lane = t & 63, wave = t >> 6;
  const int wm = wave >> 1, wn = wave & 1;
  const int quad = lane >> 4, l16 = lane & 15;
  const int pid = blockIdx.x;
  const int group = pid / 144;
  const int rem = pid - group * 144;
  const int m0 = (group * 8 + (rem & 7)) * 128;
  const int n0 = (rem >> 3) * 128;
  const bool vblk = (n0 >= 1536);
  const int srow = t >> 2, sch = (t & 3) * 8;
  f32x4 acc[4][4];
#pragma unroll
  for (int i = 0; i < 4; ++i)
#pragma unroll
    for (int j = 0; j < 4; ++j) acc[i][j] = (f32x4){0.f, 0.f, 0.f, 0.f};
  for (int k0 = 0; k0 < 768; k0 += 32) {
    const size_t ga = (size_t)(m0 + srow) * 768 + k0 + sch;
    const size_t gb = (size_t)(n0 + srow) * 768 + k0 + sch;
    __syncthreads();
    async16(Axh + ga, &As[t * 8]);
    async16(Axh + ga + (size_t)64 * 768, &As[2048 + t * 8]);
    async16(Bwh + gb, &Bs[t * 8]);
    async16(Bwh + gb + (size_t)64 * 768, &Bs[2048 + t * 8]);
    __syncthreads();
    f16x8 af[4], bfr[4];
#pragma unroll
    for (int i = 0; i < 4; ++i) af[i] = *(const f16x8*)&As[(wm * 64 + i * 16 + l16) * 32 + quad * 8];
#pragma unroll
    for (int j = 0; j < 4; ++j) bfr[j] = *(const f16x8*)&Bs[(wn * 64 + j * 16 + l16) * 32 + quad * 8];
#pragma unroll
    for (int i = 0; i < 4; ++i)
#pragma unroll
      for (int j = 0; j < 4; ++j) acc[i][j] = MFMA_F16(af[i], bfr[j], acc[i][j]);
  }
  __syncthreads();
  u16* T = smem;
#pragma unroll
  for (int i = 0; i < 4; ++i)
#pragma unroll
    for (int j = 0; j < 4; ++j)
#pragma unroll
      for (int r = 0; r < 4; ++r) {
        const int row = wm * 64 + i * 16 + quad * 4 + r;
        const int col = wn * 64 + j * 16 + l16;
        T[row * 128 + (col ^ ((row & 7) << 4))] = f2h(acc[i][j][r]);
      }
  __syncthreads();
  const int row = t >> 1, halfc = (t & 1) * 64;
  const int sw = (row & 7) << 4;
  u16* dst = vblk ? (vbuf + (size_t)(m0 + row) * 768 + (n0 - 1536) + halfc)
                  : (qkf + (size_t)(m0 + row) * 1536 + n0 + halfc);
#pragma unroll
  for (int c = 0; c < 64; c += 8)
    *(uint4*)(dst + c) = *(const uint4*)&T[row * 128 + ((halfc + c) ^ sw)];
}

// ---------------- K2: scores(fp16) = Q @ K^T per (b,h) ----------------
// Output head-minor: scbuf[((b*1024+q)*12 + h)*1024 + k]
__global__ __launch_bounds__(256) void k_qk(const u16* __restrict__ qkf,
                                            u16* __restrict__ scbuf) {
  __shared__ u16 smem[17408];   // 34 KB: [0:8192)=Q, [8192:16384)=K; whole = T[128][136]
  u16* As = smem;
  u16* Bs = smem + 8192;
  const int t = threadIdx.x, lane = t & 63, wave = t >> 6;
  const int wm = wave >> 1, wn = wave & 1;
  const int quad = lane >> 4, l16 = lane & 15;
  const int bh = blockIdx.z, b = bh / 12, h = bh % 12;
  const int m0 = blockIdx.y * 128, n0 = blockIdx.x * 128;
#pragma unroll
  for (int i = 0; i < 4; ++i) {
    const int ci = i * 256 + t;
    const int row = ci >> 3, ch = ci & 7;
    const int chs = ch ^ (row & 7);
    async16(qkf + (size_t)(b * 1024 + m0 + row) * 1536 + h * 64 + chs * 8, &As[ci * 8]);
    async16(qkf + (size_t)(b * 1024 + n0 + row) * 1536 + 768 + h * 64 + chs * 8, &Bs[ci * 8]);
  }
  f32x4 acc[4][4];
#pragma unroll
  for (int i = 0; i < 4; ++i)
#pragma unroll
    for (int j = 0; j < 4; ++j) acc[i][j] = (f32x4){0.f, 0.f, 0.f, 0.f};
  __syncthreads();
  const int sx = l16 & 7;
#pragma unroll
  for (int k0 = 0; k0 < 2; ++k0) {
    const int fch = ((k0 * 4 + quad) ^ sx) * 8;
    f16x8 af[4], bfr[4];
#pragma unroll
    for (int i = 0; i < 4; ++i) af[i] = *(const f16x8*)&As[(wm * 64 + i * 16 + l16) * 64 + fch];
#pragma unroll
    for (int j = 0; j < 4; ++j) bfr[j] = *(const f16x8*)&Bs[(wn * 64 + j * 16 + l16) * 64 + fch];
#pragma unroll
    for (int i = 0; i < 4; ++i)
#pragma unroll
      for (int j = 0; j < 4; ++j) acc[i][j] = MFMA_F16(af[i], bfr[j], acc[i][j]);
  }
  __syncthreads();
  u16* T = smem;   // [128][136]: 68 dw/row -> 4-bank shift per row, no XOR needed
#pragma unroll
  for (int i = 0; i < 4; ++i)
#pragma unroll
    for (int j = 0; j < 4; ++j)
#pragma unroll
      for (int r = 0; r < 4; ++r) {
        const int row = wm * 64 + i * 16 + quad * 4 + r;
        const int col = wn * 64 + j * 16 + l16;
        T[row * 136 + col] = f2h(acc[i][j][r]);
      }
  __syncthreads();
  const int row = t >> 1, halfc = (t & 1) * 64;
  u16* dst = scbuf + ((size_t)(b * 1024 + m0 + row) * 12 + h) * 1024 + n0 + halfc;
#pragma unroll
  for (int c = 0; c < 64; c += 8)
    *(uint4*)(dst + c) = *(const uint4*)&T[row * 136 + halfc + c];
}

// ---------------- K3: mix1 -> softmax -> mix2 on MFMA 16x16x16, in place ----------------
// One block per (b,q). Wave w owns k-tiles w*16..w*16+15.
// mix1: C1[g=quad*4+r][k=l16+kb] = MFMA16(Awl, B1, (bl-16)*log2e); E = 2^C1
// via native v_exp_f32 (inline asm; exp2f is precise-OCML and cost +13us in R8).
// mix2 (flipped): c2 = MFMA16(Pf, Aww, bw[l16]) = P2^T: lane holds
// P2[g2=l16][kb+quad*4+0..3] -> ushort4 stores.
__global__ __launch_bounds__(256) void k_mix(u16* __restrict__ scbuf,
                                             const float* __restrict__ Wl,
                                             const float* __restrict__ bl,
                                             const float* __restrict__ Ww,
                                             const float* __restrict__ bw) {
  __shared__ u16 S[12 * 1032];          // rows padded +8 u16 (stride 1032): <=2-way banks
  __shared__ float red[4][16];
  const int t = threadIdx.x, lane = t & 63, wave = t >> 6;
  const int quad = lane >> 4, l16 = lane & 15;
  const int bq = blockIdx.x, b = bq >> 10, q = bq & 1023;
  const size_t qslab = (size_t)(b * 1024 + q) * 12288;   // 12*1024 u16
  // stage S[12][1024] (+pad) : 1548 chunks of 16B, lane-linear LDS dest
#pragma unroll
  for (int i = 0; i < 7; ++i) {
    const int ci = i * 256 + t;
    if (ci < 1548) {
      const int row = ci / 129, c = ci - row * 129;
      async16(scbuf + qslab + row * 1024 + c * 8, &S[ci * 8]);  // c==128 pad: never read
    }
  }
  const float L2E = 1.44269504088896f;
  // constant fragments (h>=12 and g>=12 zeroed -> no NaN paths)
  const bool actA = (quad < 3);   // valid g rows (mix1 C) / valid h (kd slots)
  const bool actS = (l16 < 12);   // valid g2 columns (mix2 C)
  f16x4 Awl = (f16x4){0, 0, 0, 0}, Aww = (f16x4){0, 0, 0, 0};
  if (actA && l16 < 12) {
    const float4 wl4 = *(const float4*)&Wl[l16 * 12 + quad * 4];
    const float4 ww4 = *(const float4*)&Ww[l16 * 12 + quad * 4];
    Awl[0] = (f16)(wl4.x * L2E); Awl[1] = (f16)(wl4.y * L2E);
    Awl[2] = (f16)(wl4.z * L2E); Awl[3] = (f16)(wl4.w * L2E);
    Aww[0] = (f16)ww4.x; Aww[1] = (f16)ww4.y; Aww[2] = (f16)ww4.z; Aww[3] = (f16)ww4.w;
  }
  float blv[4];
#pragma unroll
  for (int r = 0; r < 4; ++r)
    blv[r] = actA ? (bl[quad * 4 + r] - 16.f) * L2E : 0.f;   // constant-shift softmax
  const float bws = actS ? bw[l16] : 0.f;
  int roff[4];
#pragma unroll
  for (int j = 0; j < 4; ++j) roff[j] = (quad * 4 + j) * 1032 + l16;
  __syncthreads();
  // pass 1: mix1 MFMA + native exp2; E kept in f32 registers; accumulate row sums
  float Ev[16][4];
  float a0 = 0.f, a1 = 0.f, a2 = 0.f, a3 = 0.f;
#pragma unroll
  for (int i = 0; i < 16; ++i) {
    const int kb = (wave * 16 + i) * 16;
    f16x4 B1 = (f16x4){0, 0, 0, 0};
    if (actA) {
#pragma unroll
      for (int j = 0; j < 4; ++j) B1[j] = __builtin_bit_cast(f16, S[roff[j] + kb]);
    }
    f32x4 c1 = (f32x4){blv[0], blv[1], blv[2], blv[3]};
    c1 = MFMA16(Awl, B1, c1);
    const float e0 = exp2_native(c1[0]), e1 = exp2_native(c1[1]);
    const float e2 = exp2_native(c1[2]), e3 = exp2_native(c1[3]);
    Ev[i][0] = e0; Ev[i][1] = e1; Ev[i][2] = e2; Ev[i][3] = e3;
    a0 += e0; a1 += e1; a2 += e2; a3 += e3;
  }
  // reduce over the 16 k-columns held by l16 lanes
#pragma unroll
  for (int m = 1; m <= 8; m <<= 1) {
    a0 += __shfl_xor(a0, m); a1 += __shfl_xor(a1, m);
    a2 += __shfl_xor(a2, m); a3 += __shfl_xor(a3, m);
  }
  if (l16 == 0) {
    red[wave][quad * 4 + 0] = a0; red[wave][quad * 4 + 1] = a1;
    red[wave][quad * 4 + 2] = a2; red[wave][quad * 4 + 3] = a3;
  }
  __syncthreads();
  float dinv[4];
#pragma unroll
  for (int r = 0; r < 4; ++r) {
    const int g = quad * 4 + r;
    dinv[r] = 1.0f / (red[0][g] + red[1][g] + red[2][g] + red[3][g]);
  }
  // pass 2: P = E*dinv (fp16) -> flipped mix2 MFMA -> ushort4 stores
  u16* const outp = scbuf + qslab + (size_t)l16 * 1024 + quad * 4;   // + kb
#pragma unroll
  for (int i = 0; i < 16; ++i) {
    const int kb = (wave * 16 + i) * 16;
    const unsigned lo = pk2h(Ev[i][0] * dinv[0], Ev[i][1] * dinv[1]);
    const unsigned hi = pk2h(Ev[i][2] * dinv[2], Ev[i][3] * dinv[3]);
    u32x2 pw = {lo, hi};
    const f16x4 Pf = __builtin_bit_cast(f16x4, pw);
    f32x4 c2 = (f32x4){bws, bws, bws, bws};
    c2 = MFMA16(Pf, Aww, c2);   // P^T * Ww^T = P2^T
    if (actS) {
      ushort4 st = make_ushort4(f2h(c2[0]), f2h(c2[1]), f2h(c2[2]), f2h(c2[3]));
      *(ushort4*)(outp + kb) = st;
    }
  }
}

// ---------------- K4: ctx = P2(fp16) @ V(fp16) per (b,h); V transposed in-LDS ----------------
__global__ __launch_bounds__(256) void k_pv(const u16* __restrict__ probs,
                                            const u16* __restrict__ vbuf,
                                            u16* __restrict__ ctx) {
  __shared__ u16 As[4096];      // 128x32 P tile
  __shared__ u16 Bs[64 * 40];   // V^T tile: [e][s-chunk 32], row stride 40
  const int t = threadIdx.x, lane = t & 63, wave = t >> 6;
  const int wm = wave >> 1, wn = wave & 1;
  const int quad = lane >> 4, l16 = lane & 15;
  const int bh = blockIdx.y, b = bh / 12, h = bh % 12;
  const int m0 = blockIdx.x * 128;
  const int srow = t >> 2, sch = (t & 3) * 8;
  const int ev = t & 63, s8 = (t >> 6) * 8;
  f32x4 acc[4][2];
#pragma unroll
  for (int i = 0; i < 4; ++i)
#pragma unroll
    for (int j = 0; j < 2; ++j) acc[i][j] = (f32x4){0.f, 0.f, 0.f, 0.f};
  for (int k0 = 0; k0 < 1024; k0 += 32) {
    const u16* vp = vbuf + (size_t)(b * 1024 + k0 + s8) * 768 + h * 64 + ev;
    u16 vcol[8];
#pragma unroll
    for (int i = 0; i < 8; ++i) vcol[i] = vp[(size_t)i * 768];
    __syncthreads();
    const u16* ga = probs + ((size_t)(b * 1024 + m0 + srow) * 12 + h) * 1024 + k0 + sch;
    async16(ga, &As[t * 8]);
    async16(ga + (size_t)64 * 12 * 1024, &As[2048 + t * 8]);
    *(ushort4*)&Bs[ev * 40 + s8] = make_ushort4(vcol[0], vcol[1], vcol[2], vcol[3]);
    *(ushort4*)&Bs[ev * 40 + s8 + 4] = make_ushort4(vcol[4], vcol[5], vcol[6], vcol[7]);
    __syncthreads();
    f16x8 af[4], bfr[2];
#pragma unroll
    for (int i = 0; i < 4; ++i) af[i] = *(const f16x8*)&As[(wm * 64 + i * 16 + l16) * 32 + quad * 8];
#pragma unroll
    for (int j = 0; j < 2; ++j) bfr[j] = *(const f16x8*)&Bs[(wn * 32 + j * 16 + l16) * 40 + quad * 8];
#pragma unroll
    for (int i = 0; i < 4; ++i)
#pragma unroll
      for (int j = 0; j < 2; ++j) acc[i][j] = MFMA_F16(af[i], bfr[j], acc[i][j]);
  }
#pragma unroll
  for (int i = 0; i < 4; ++i)
#pragma unroll
    for (int j = 0; j < 2; ++j)
#pragma unroll
      for (int r = 0; r < 4; ++r) {
        int q = m0 + wm * 64 + i * 16 + quad * 4 + r;
        int e = wn * 32 + j * 16 + l16;
        ctx[(size_t)(b * 1024 + q) * 768 + h * 64 + e] = f2h(acc[i][j][r]);
      }
}

// ---------------- K5: out = ctx @ Wp^T + bp (fp16 MFMA, fp32 out) ----------------
__global__ __launch_bounds__(256) void k_oproj(const u16* __restrict__ A,
                                               const u16* __restrict__ Bm,
                                               const float* __restrict__ bp,
                                               float* __restrict__ out) {
  __shared__ u16 As[4096];
  __shared__ u16 Bs[4096];
  const int t = threadIdx.x, lane = t & 63, wave = t >> 6;
  const int wm = wave >> 1, wn = wave & 1;
  const int quad = lane >> 4, l16 = lane & 15;
  const int m0 = blockIdx.y * 128, n0 = blockIdx.x * 128;
  const int srow = t >> 2, sch = (t & 3) * 8;
  f32x4 acc[4][4];
#pragma unroll
  for (int i = 0; i < 4; ++i)
#pragma unroll
    for (int j = 0; j < 4; ++j) acc[i][j] = (f32x4){0.f, 0.f, 0.f, 0.f};
  for (int k0 = 0; k0 < 768; k0 += 32) {
    __syncthreads();
    const u16* ga = A + (size_t)(m0 + srow) * 768 + k0 + sch;
    const u16* gb = Bm + (size_t)(n0 + srow) * 768 + k0 + sch;
    async16(ga, &As[t * 8]);
    async16(ga + (size_t)64 * 768, &As[2048 + t * 8]);
    async16(gb, &Bs[t * 8]);
    async16(gb + (size_t)64 * 768, &Bs[2048 + t * 8]);
    __syncthreads();
    f16x8 af[4], bfr[4];
#pragma unroll
    for (int i = 0; i < 4; ++i) af[i] = *(const f16x8*)&As[(wm * 64 + i * 16 + l16) * 32 + quad * 8];
#pragma unroll
    for (int j = 0; j < 4; ++j) bfr[j] = *(const f16x8*)&Bs[(wn * 64 + j * 16 + l16) * 32 + quad * 8];
#pragma unroll
    for (int i = 0; i < 4; ++i)
#pragma unroll
      for (int j = 0; j < 4; ++j) acc[i][j] = MFMA_F16(af[i], bfr[j], acc[i][j]);
  }
#pragma unroll
  for (int i = 0; i < 4; ++i)
#pragma unroll
    for (int j = 0; j < 4; ++j)
#pragma unroll
      for (int r = 0; r < 4; ++r) {
        const int row = m0 + wm * 64 + i * 16 + quad * 4 + r;
        const int col = n0 + wn * 64 + j * 16 + l16;
        out[(size_t)row * 768 + col] = acc[i][j][r] + bp[col];
      }
}

extern "C" void kernel_launch(void* const* d_in, const int* in_sizes, int n_in,
                              void* d_out, int out_size, void* d_ws, size_t ws_size,
                              hipStream_t stream) {
  const float* x    = (const float*)d_in[0];
  const float* Wqkv = (const float*)d_in[1];
  const float* Wl   = (const float*)d_in[2];
  const float* bl   = (const float*)d_in[3];
  const float* Ww   = (const float*)d_in[4];
  const float* bw   = (const float*)d_in[5];
  const float* Wp   = (const float*)d_in[6];
  const float* bp   = (const float*)d_in[7];
  float* out = (float*)d_out;

  char* ws = (char*)d_ws;
  u16* scbuf = (u16*)(ws + 0);               // 100,663,296 B, [b][q][h][k]
  u16* qkf   = (u16*)(ws + 100663296ull);    //  12,582,912 B
  u16* vbuf  = (u16*)(ws + 113246208ull);    //   6,291,456 B
  u16* ctx   = (u16*)(ws + 119537664ull);    //   6,291,456 B
  u16* x_h   = (u16*)(ws + 125829120ull);    //   6,291,456 B
  u16* wq_h  = (u16*)(ws + 132120576ull);    //   3,538,944 B
  u16* wp_h  = (u16*)(ws + 135659520ull);    //   1,179,648 B

  hipLaunchKernelGGL(k_prep, dim3(5376), dim3(256), 0, stream,
                     x, Wqkv, Wp, x_h, wq_h, wp_h);
  hipLaunchKernelGGL(k_qkv,  dim3(576),      dim3(256), 0, stream, x_h, wq_h, qkf, vbuf);
  hipLaunchKernelGGL(k_qk,   dim3(8, 8, 48), dim3(256), 0, stream, qkf, scbuf);
  hipLaunchKernelGGL(k_mix,  dim3(4096),     dim3(256), 0, stream, scbuf, Wl, bl, Ww, bw);
  hipLaunchKernelGGL(k_pv,   dim3(8, 48),    dim3(256), 0, stream, scbuf, vbuf, ctx);
  hipLaunchKernelGGL(k_oproj, dim3(6, 32),   dim3(256), 0, stream, ctx, wp_h, bp, out);
}

// Round 10
// 242.810 us; speedup vs baseline: 1.0450x; 1.0450x over previous
//
#include <hip/hip_runtime.h>
#include <math.h>

// B=4, S=1024, D=768, H=12, E=64, 3D=2304
// Workspace layout (bytes), total ~137 MB:
//   scbuf fp16 scores -> fp16 probs in place : 100,663,296 @ 0
//     layout [b][q][h][k] head-minor (head stride 1024 u16, q stride 12*1024)
//   qkf  fp16 [4096][1536] (Q,K)  : 12,582,912 @ 100,663,296
//   vbuf fp16 [4096][768]  (V)    :  6,291,456 @ 113,246,208
//   ctx  fp16 [4096][768]         :  6,291,456 @ 119,537,664
//   x_h  fp16 :  6,291,456 @ 125,829,120
//   wq_h fp16 :  3,538,944 @ 132,120,576
//   wp_h fp16 :  1,179,648 @ 135,659,520
//
// R10 (k_mix only): revert mix2 to R6's proven store orientation (flip was the
// R8/R9 regression: 12x32B scattered segments/instr, 48/64 lanes). Keep native
// v_exp_f32 + L2E fold. NEW: drop the S LDS staging entirely — S is read
// exactly once, B1 fragments load direct from global (4x32B segments/instr,
// same coalescing as the staging's global side) -> ~50 fewer VMEM instrs,
// 1 fewer barrier, LDS 25KB -> 256B (occupancy up).

typedef _Float16 f16;
typedef __attribute__((ext_vector_type(8))) _Float16 f16x8;
typedef __attribute__((ext_vector_type(4))) _Float16 f16x4;
typedef __attribute__((ext_vector_type(2))) _Float16 f16x2;
typedef __attribute__((ext_vector_type(4))) float f32x4;
typedef __attribute__((ext_vector_type(2))) float f32x2;
typedef __attribute__((ext_vector_type(2))) unsigned u32x2;
typedef unsigned short u16;

__device__ __forceinline__ u16 f2h(float f) {      // RTN convert
  f16 h = (f16)f;
  return __builtin_bit_cast(u16, h);
}
__device__ __forceinline__ unsigned pk2h(float a, float b) {
  return __builtin_bit_cast(unsigned, __builtin_amdgcn_cvt_pkrtz(a, b));
}
__device__ __forceinline__ float exp2_native(float x) {   // D = 2^S0
  float r;
  asm("v_exp_f32 %0, %1" : "=v"(r) : "v"(x));
  return r;
}

__device__ __forceinline__ void async16(const void* g, void* l) {
  __builtin_amdgcn_global_load_lds(
      (const __attribute__((address_space(1))) unsigned int*)g,
      (__attribute__((address_space(3))) unsigned int*)l, 16, 0, 0);
}

#define MFMA_F16(a, b, c) __builtin_amdgcn_mfma_f32_16x16x32_f16((a), (b), (c), 0, 0, 0)
#define MFMA16(a, b, c) __builtin_amdgcn_mfma_f32_16x16x16f16((a), (b), (c), 0, 0, 0)

// ---------------- prep: cast x, Wqkv, Wp to fp16 ----------------
__global__ __launch_bounds__(256) void k_prep(const float* __restrict__ x,
                                              const float* __restrict__ Wqkv,
                                              const float* __restrict__ Wp,
                                              u16* __restrict__ xh,
                                              u16* __restrict__ wh,
                                              u16* __restrict__ wph) {
  const int blk = blockIdx.x, t = threadIdx.x;
  if (blk < 3072) {
    int i = blk * 256 + t;
    float4 v = ((const float4*)x)[i];
    ((ushort4*)xh)[i] = make_ushort4(f2h(v.x), f2h(v.y), f2h(v.z), f2h(v.w));
  } else if (blk < 4800) {
    int i = (blk - 3072) * 256 + t;
    float4 v = ((const float4*)Wqkv)[i];
    ((ushort4*)wh)[i] = make_ushort4(f2h(v.x), f2h(v.y), f2h(v.z), f2h(v.w));
  } else {
    int i = (blk - 4800) * 256 + t;
    float4 v = ((const float4*)Wp)[i];
    ((ushort4*)wph)[i] = make_ushort4(f2h(v.x), f2h(v.y), f2h(v.z), f2h(v.w));
  }
}

// ---------------- K1: qkv = x @ Wqkv^T, fp16 single-MFMA ----------------
__global__ __launch_bounds__(256) void k_qkv(const u16* __restrict__ Axh,
                                             const u16* __restrict__ Bwh,
                                             u16* __restrict__ qkf,
                                             u16* __restrict__ vbuf) {
  __shared__ u16 smem[16384];
  u16* As = smem;
  u16* Bs = smem + 4096;
  const int t = threadIdx.x, lane = t & 63, wave = t >> 6;
  const int wm = wave >> 1, wn = wave & 1;
  const int quad = lane >> 4, l16 = lane & 15;
  const int pid = blockIdx.x;
  const int group = pid / 144;
  const int rem = pid - group * 144;
  const int m0 = (group * 8 + (rem & 7)) * 128;
  const int n0 = (rem >> 3) * 128;
  const bool vblk = (n0 >= 1536);
  const int srow = t >> 2, sch = (t & 3) * 8;
  f32x4 acc[4][4];
#pragma unroll
  for (int i = 0; i < 4; ++i)
#pragma unroll
    for (int j = 0; j < 4; ++j) acc[i][j] = (f32x4){0.f, 0.f, 0.f, 0.f};
  for (int k0 = 0; k0 < 768; k0 += 32) {
    const size_t ga = (size_t)(m0 + srow) * 768 + k0 + sch;
    const size_t gb = (size_t)(n0 + srow) * 768 + k0 + sch;
    __syncthreads();
    async16(Axh + ga, &As[t * 8]);
    async16(Axh + ga + (size_t)64 * 768, &As[2048 + t * 8]);
    async16(Bwh + gb, &Bs[t * 8]);
    async16(Bwh + gb + (size_t)64 * 768, &Bs[2048 + t * 8]);
    __syncthreads();
    f16x8 af[4], bfr[4];
#pragma unroll
    for (int i = 0; i < 4; ++i) af[i] = *(const f16x8*)&As[(wm * 64 + i * 16 + l16) * 32 + quad * 8];
#pragma unroll
    for (int j = 0; j < 4; ++j) bfr[j] = *(const f16x8*)&Bs[(wn * 64 + j * 16 + l16) * 32 + quad * 8];
#pragma unroll
    for (int i = 0; i < 4; ++i)
#pragma unroll
      for (int j = 0; j < 4; ++j) acc[i][j] = MFMA_F16(af[i], bfr[j], acc[i][j]);
  }
  __syncthreads();
  u16* T = smem;
#pragma unroll
  for (int i = 0; i < 4; ++i)
#pragma unroll
    for (int j = 0; j < 4; ++j)
#pragma unroll
      for (int r = 0; r < 4; ++r) {
        const int row = wm * 64 + i * 16 + quad * 4 + r;
        const int col = wn * 64 + j * 16 + l16;
        T[row * 128 + (col ^ ((row & 7) << 4))] = f2h(acc[i][j][r]);
      }
  __syncthreads();
  const int row = t >> 1, halfc = (t & 1) * 64;
  const int sw = (row & 7) << 4;
  u16* dst = vblk ? (vbuf + (size_t)(m0 + row) * 768 + (n0 - 1536) + halfc)
                  : (qkf + (size_t)(m0 + row) * 1536 + n0 + halfc);
#pragma unroll
  for (int c = 0; c < 64; c += 8)
    *(uint4*)(dst + c) = *(const uint4*)&T[row * 128 + ((halfc + c) ^ sw)];
}

// ---------------- K2: scores(fp16) = Q @ K^T per (b,h) ----------------
// Output head-minor: scbuf[((b*1024+q)*12 + h)*1024 + k]
__global__ __launch_bounds__(256) void k_qk(const u16* __restrict__ qkf,
                                            u16* __restrict__ scbuf) {
  __shared__ u16 smem[17408];   // 34 KB: [0:8192)=Q, [8192:16384)=K; whole = T[128][136]
  u16* As = smem;
  u16* Bs = smem + 8192;
  const int t = threadIdx.x, lane = t & 63, wave = t >> 6;
  const int wm = wave >> 1, wn = wave & 1;
  const int quad = lane >> 4, l16 = lane & 15;
  const int bh = blockIdx.z, b = bh / 12, h = bh % 12;
  const int m0 = blockIdx.y * 128, n0 = blockIdx.x * 128;
#pragma unroll
  for (int i = 0; i < 4; ++i) {
    const int ci = i * 256 + t;
    const int row = ci >> 3, ch = ci & 7;
    const int chs = ch ^ (row & 7);
    async16(qkf + (size_t)(b * 1024 + m0 + row) * 1536 + h * 64 + chs * 8, &As[ci * 8]);
    async16(qkf + (size_t)(b * 1024 + n0 + row) * 1536 + 768 + h * 64 + chs * 8, &Bs[ci * 8]);
  }
  f32x4 acc[4][4];
#pragma unroll
  for (int i = 0; i < 4; ++i)
#pragma unroll
    for (int j = 0; j < 4; ++j) acc[i][j] = (f32x4){0.f, 0.f, 0.f, 0.f};
  __syncthreads();
  const int sx = l16 & 7;
#pragma unroll
  for (int k0 = 0; k0 < 2; ++k0) {
    const int fch = ((k0 * 4 + quad) ^ sx) * 8;
    f16x8 af[4], bfr[4];
#pragma unroll
    for (int i = 0; i < 4; ++i) af[i] = *(const f16x8*)&As[(wm * 64 + i * 16 + l16) * 64 + fch];
#pragma unroll
    for (int j = 0; j < 4; ++j) bfr[j] = *(const f16x8*)&Bs[(wn * 64 + j * 16 + l16) * 64 + fch];
#pragma unroll
    for (int i = 0; i < 4; ++i)
#pragma unroll
      for (int j = 0; j < 4; ++j) acc[i][j] = MFMA_F16(af[i], bfr[j], acc[i][j]);
  }
  __syncthreads();
  u16* T = smem;   // [128][136]: 68 dw/row -> 4-bank shift per row, no XOR needed
#pragma unroll
  for (int i = 0; i < 4; ++i)
#pragma unroll
    for (int j = 0; j < 4; ++j)
#pragma unroll
      for (int r = 0; r < 4; ++r) {
        const int row = wm * 64 + i * 16 + quad * 4 + r;
        const int col = wn * 64 + j * 16 + l16;
        T[row * 136 + col] = f2h(acc[i][j][r]);
      }
  __syncthreads();
  const int row = t >> 1, halfc = (t & 1) * 64;
  u16* dst = scbuf + ((size_t)(b * 1024 + m0 + row) * 12 + h) * 1024 + n0 + halfc;
#pragma unroll
  for (int c = 0; c < 64; c += 8)
    *(uint4*)(dst + c) = *(const uint4*)&T[row * 136 + halfc + c];
}

// ---------------- K3: mix1 -> softmax -> mix2 on MFMA 16x16x16, in place ----------------
// One block per (b,q). Wave w owns k-tiles w*16..w*16+15. No LDS staging of S:
// B1 fragments load direct from global (each S element read exactly once;
// 16-lane groups read 32B contiguous -> 4x32B segments per load instr).
// mix1: C1[g=quad*4+r][k=l16+kb] = MFMA16(Awl, B1, (bl-16)*L2E); E = 2^C1 native.
// mix2 (R6 orientation): c2 = MFMA16(Aww, Pf, bw) ; C rows g2=quad*4+r.
// In-place safe: pass-1 loads are data-deps of red[] write; __syncthreads()
// orders them before any pass-2 store.
__global__ __launch_bounds__(256) void k_mix(u16* __restrict__ scbuf,
                                             const float* __restrict__ Wl,
                                             const float* __restrict__ bl,
                                             const float* __restrict__ Ww,
                                             const float* __restrict__ bw) {
  __shared__ float red[4][16];
  const int t = threadIdx.x, lane = t & 63, wave = t >> 6;
  const int quad = lane >> 4, l16 = lane & 15;
  const int bq = blockIdx.x, b = bq >> 10, q = bq & 1023;
  const size_t qslab = (size_t)(b * 1024 + q) * 12288;   // 12*1024 u16
  const float L2E = 1.44269504088896f;
  const bool actA = (quad < 3);   // valid g rows / valid h kd-slots
  f16x4 Awl = (f16x4){0, 0, 0, 0}, Aww = (f16x4){0, 0, 0, 0};
  if (actA && l16 < 12) {
    const float4 wl4 = *(const float4*)&Wl[l16 * 12 + quad * 4];
    const float4 ww4 = *(const float4*)&Ww[l16 * 12 + quad * 4];
    Awl[0] = (f16)(wl4.x * L2E); Awl[1] = (f16)(wl4.y * L2E);
    Awl[2] = (f16)(wl4.z * L2E); Awl[3] = (f16)(wl4.w * L2E);
    Aww[0] = (f16)ww4.x; Aww[1] = (f16)ww4.y; Aww[2] = (f16)ww4.z; Aww[3] = (f16)ww4.w;
  }
  float blv[4], bwv[4];
#pragma unroll
  for (int r = 0; r < 4; ++r) {
    blv[r] = actA ? (bl[quad * 4 + r] - 16.f) * L2E : 0.f;   // constant-shift softmax
    bwv[r] = actA ? bw[quad * 4 + r] : 0.f;
  }
  // pass 1: B1 direct-from-global mix1 MFMA + native exp2; row sums
  const u16* const Sg = scbuf + qslab + (size_t)(quad * 4) * 1024 + l16;  // +j*1024+kb
  float Ev[16][4];
  float a0 = 0.f, a1 = 0.f, a2 = 0.f, a3 = 0.f;
#pragma unroll
  for (int i = 0; i < 16; ++i) {
    const int kb = (wave * 16 + i) * 16;
    f16x4 B1 = (f16x4){0, 0, 0, 0};
    if (actA) {
#pragma unroll
      for (int j = 0; j < 4; ++j) B1[j] = __builtin_bit_cast(f16, Sg[j * 1024 + kb]);
    }
    f32x4 c1 = (f32x4){blv[0], blv[1], blv[2], blv[3]};
    c1 = MFMA16(Awl, B1, c1);
    const float e0 = exp2_native(c1[0]), e1 = exp2_native(c1[1]);
    const float e2 = exp2_native(c1[2]), e3 = exp2_native(c1[3]);
    Ev[i][0] = e0; Ev[i][1] = e1; Ev[i][2] = e2; Ev[i][3] = e3;
    a0 += e0; a1 += e1; a2 += e2; a3 += e3;
  }
  // reduce over the 16 k-columns held by l16 lanes
#pragma unroll
  for (int m = 1; m <= 8; m <<= 1) {
    a0 += __shfl_xor(a0, m); a1 += __shfl_xor(a1, m);
    a2 += __shfl_xor(a2, m); a3 += __shfl_xor(a3, m);
  }
  if (l16 == 0) {
    red[wave][quad * 4 + 0] = a0; red[wave][quad * 4 + 1] = a1;
    red[wave][quad * 4 + 2] = a2; red[wave][quad * 4 + 3] = a3;
  }
  __syncthreads();
  float dinv[4];
#pragma unroll
  for (int r = 0; r < 4; ++r) {
    const int g = quad * 4 + r;
    dinv[r] = 1.0f / (red[0][g] + red[1][g] + red[2][g] + red[3][g]);
  }
  // pass 2: P = E*dinv (fp16, B-frag in-register) -> mix2 MFMA -> u16 stores
  u16* const outp = scbuf + qslab + (size_t)quad * 4096 + l16;   // + r*1024 + kb
#pragma unroll
  for (int i = 0; i < 16; ++i) {
    const int kb = (wave * 16 + i) * 16;
    const unsigned lo = pk2h(Ev[i][0] * dinv[0], Ev[i][1] * dinv[1]);
    const unsigned hi = pk2h(Ev[i][2] * dinv[2], Ev[i][3] * dinv[3]);
    u32x2 pw = {lo, hi};
    const f16x4 Pf = __builtin_bit_cast(f16x4, pw);
    f32x4 c2 = (f32x4){bwv[0], bwv[1], bwv[2], bwv[3]};
    c2 = MFMA16(Aww, Pf, c2);
    if (actA) {
#pragma unroll
      for (int r = 0; r < 4; ++r) outp[r * 1024 + kb] = f2h(c2[r]);
    }
  }
}

// ---------------- K4: ctx = P2(fp16) @ V(fp16) per (b,h); V transposed in-LDS ----------------
__global__ __launch_bounds__(256) void k_pv(const u16* __restrict__ probs,
                                            const u16* __restrict__ vbuf,
                                            u16* __restrict__ ctx) {
  __shared__ u16 As[4096];      // 128x32 P tile
  __shared__ u16 Bs[64 * 40];   // V^T tile: [e][s-chunk 32], row stride 40
  const int t = threadIdx.x, lane = t & 63, wave = t >> 6;
  const int wm = wave >> 1, wn = wave & 1;
  const int quad = lane >> 4, l16 = lane & 15;
  const int bh = blockIdx.y, b = bh / 12, h = bh % 12;
  const int m0 = blockIdx.x * 128;
  const int srow = t >> 2, sch = (t & 3) * 8;
  const int ev = t & 63, s8 = (t >> 6) * 8;
  f32x4 acc[4][2];
#pragma unroll
  for (int i = 0; i < 4; ++i)
#pragma unroll
    for (int j = 0; j < 2; ++j) acc[i][j] = (f32x4){0.f, 0.f, 0.f, 0.f};
  for (int k0 = 0; k0 < 1024; k0 += 32) {
    const u16* vp = vbuf + (size_t)(b * 1024 + k0 + s8) * 768 + h * 64 + ev;
    u16 vcol[8];
#pragma unroll
    for (int i = 0; i < 8; ++i) vcol[i] = vp[(size_t)i * 768];
    __syncthreads();
    const u16* ga = probs + ((size_t)(b * 1024 + m0 + srow) * 12 + h) * 1024 + k0 + sch;
    async16(ga, &As[t * 8]);
    async16(ga + (size_t)64 * 12 * 1024, &As[2048 + t * 8]);
    *(ushort4*)&Bs[ev * 40 + s8] = make_ushort4(vcol[0], vcol[1], vcol[2], vcol[3]);
    *(ushort4*)&Bs[ev * 40 + s8 + 4] = make_ushort4(vcol[4], vcol[5], vcol[6], vcol[7]);
    __syncthreads();
    f16x8 af[4], bfr[2];
#pragma unroll
    for (int i = 0; i < 4; ++i) af[i] = *(const f16x8*)&As[(wm * 64 + i * 16 + l16) * 32 + quad * 8];
#pragma unroll
    for (int j = 0; j < 2; ++j) bfr[j] = *(const f16x8*)&Bs[(wn * 32 + j * 16 + l16) * 40 + quad * 8];
#pragma unroll
    for (int i = 0; i < 4; ++i)
#pragma unroll
      for (int j = 0; j < 2; ++j) acc[i][j] = MFMA_F16(af[i], bfr[j], acc[i][j]);
  }
#pragma unroll
  for (int i = 0; i < 4; ++i)
#pragma unroll
    for (int j = 0; j < 2; ++j)
#pragma unroll
      for (int r = 0; r < 4; ++r) {
        int q = m0 + wm * 64 + i * 16 + quad * 4 + r;
        int e = wn * 32 + j * 16 + l16;
        ctx[(size_t)(b * 1024 + q) * 768 + h * 64 + e] = f2h(acc[i][j][r]);
      }
}

// ---------------- K5: out = ctx @ Wp^T + bp (fp16 MFMA, fp32 out) ----------------
__global__ __launch_bounds__(256) void k_oproj(const u16* __restrict__ A,
                                               const u16* __restrict__ Bm,
                                               const float* __restrict__ bp,
                                               float* __restrict__ out) {
  __shared__ u16 As[4096];
  __shared__ u16 Bs[4096];
  const int t = threadIdx.x, lane = t & 63, wave = t >> 6;
  const int wm = wave >> 1, wn = wave & 1;
  const int quad = lane >> 4, l16 = lane & 15;
  const int m0 = blockIdx.y * 128, n0 = blockIdx.x * 128;
  const int srow = t >> 2, sch = (t & 3) * 8;
  f32x4 acc[4][4];
#pragma unroll
  for (int i = 0; i < 4; ++i)
#pragma unroll
    for (int j = 0; j < 4; ++j) acc[i][j] = (f32x4){0.f, 0.f, 0.f, 0.f};
  for (int k0 = 0; k0 < 768; k0 += 32) {
    __syncthreads();
    const u16* ga = A + (size_t)(m0 + srow) * 768 + k0 + sch;
    const u16* gb = Bm + (size_t)(n0 + srow) * 768 + k0 + sch;
    async16(ga, &As[t * 8]);
    async16(ga + (size_t)64 * 768, &As[2048 + t * 8]);
    async16(gb, &Bs[t * 8]);
    async16(gb + (size_t)64 * 768, &Bs[2048 + t * 8]);
    __syncthreads();
    f16x8 af[4], bfr[4];
#pragma unroll
    for (int i = 0; i < 4; ++i) af[i] = *(const f16x8*)&As[(wm * 64 + i * 16 + l16) * 32 + quad * 8];
#pragma unroll
    for (int j = 0; j < 4; ++j) bfr[j] = *(const f16x8*)&Bs[(wn * 64 + j * 16 + l16) * 32 + quad * 8];
#pragma unroll
    for (int i = 0; i < 4; ++i)
#pragma unroll
      for (int j = 0; j < 4; ++j) acc[i][j] = MFMA_F16(af[i], bfr[j], acc[i][j]);
  }
#pragma unroll
  for (int i = 0; i < 4; ++i)
#pragma unroll
    for (int j = 0; j < 4; ++j)
#pragma unroll
      for (int r = 0; r < 4; ++r) {
        const int row = m0 + wm * 64 + i * 16 + quad * 4 + r;
        const int col = n0 + wn * 64 + j * 16 + l16;
        out[(size_t)row * 768 + col] = acc[i][j][r] + bp[col];
      }
}

extern "C" void kernel_launch(void* const* d_in, const int* in_sizes, int n_in,
                              void* d_out, int out_size, void* d_ws, size_t ws_size,
                              hipStream_t stream) {
  const float* x    = (const float*)d_in[0];
  const float* Wqkv = (const float*)d_in[1];
  const float* Wl   = (const float*)d_in[2];
  const float* bl   = (const float*)d_in[3];
  const float* Ww   = (const float*)d_in[4];
  const float* bw   = (const float*)d_in[5];
  const float* Wp   = (const float*)d_in[6];
  const float* bp   = (const float*)d_in[7];
  float* out = (float*)d_out;

  char* ws = (char*)d_ws;
  u16* scbuf = (u16*)(ws + 0);               // 100,663,296 B, [b][q][h][k]
  u16* qkf   = (u16*)(ws + 100663296ull);    //  12,582,912 B
  u16* vbuf  = (u16*)(ws + 113246208ull);    //   6,291,456 B
  u16* ctx   = (u16*)(ws + 119537664ull);    //   6,291,456 B
  u16* x_h   = (u16*)(ws + 125829120ull);    //   6,291,456 B
  u16* wq_h  = (u16*)(ws + 132120576ull);    //   3,538,944 B
  u16* wp_h  = (u16*)(ws + 135659520ull);    //   1,179,648 B

  hipLaunchKernelGGL(k_prep, dim3(5376), dim3(256), 0, stream,
                     x, Wqkv, Wp, x_h, wq_h, wp_h);
  hipLaunchKernelGGL(k_qkv,  dim3(576),      dim3(256), 0, stream, x_h, wq_h, qkf, vbuf);
  hipLaunchKernelGGL(k_qk,   dim3(8, 8, 48), dim3(256), 0, stream, qkf, scbuf);
  hipLaunchKernelGGL(k_mix,  dim3(4096),     dim3(256), 0, stream, scbuf, Wl, bl, Ww, bw);
  hipLaunchKernelGGL(k_pv,   dim3(8, 48),    dim3(256), 0, stream, scbuf, vbuf, ctx);
  hipLaunchKernelGGL(k_oproj, dim3(6, 32),   dim3(256), 0, stream, ctx, wp_h, bp, out);
}